// Round 2
// baseline (78.984 us; speedup 1.0000x reference)
//
#include <hip/hip_runtime.h>

typedef float f4 __attribute__((ext_vector_type(4)));

#define Hdim 64
#define Wdim 64
#define Cdim 256
#define HW (Hdim * Wdim)

__global__ __launch_bounds__(512) void selfattn_kernel(const float* __restrict__ x,
                                                       float* __restrict__ out)
{
    const int h = blockIdx.x;   // 0..63
    const int b = blockIdx.y;   // 0..3
    const int t = threadIdx.x;  // 0..511

    __shared__ float simRed[49][64];   // reduced sim
    __shared__ float attnBuf[49][64];  // softmax weights
    __shared__ float redBuf[7][64];    // per-kchunk max
    __shared__ float psumBuf[7][64];   // per-kchunk expsum

    const float* xb = x + (size_t)b * (Cdim * HW);

    // ---------------- Phase A: sim[k][w] ----------------
    // f[j] holds row position (w0 - 4 + j); loads from w0-4, w0, w0+4.
    {
        const int w4 = t & 15;       // w-group
        const int g  = t >> 4;       // 0..31
        const int cp = g & 3;        // channel partition (lane bits 4..5)
        const int dy = g >> 2;       // wave-uniform; dy==7 -> idle wave
        const int w0 = w4 * 4;

        if (dy < 7) {
            float sim[7][4];
            #pragma unroll
            for (int i = 0; i < 7; ++i)
                #pragma unroll
                for (int p = 0; p < 4; ++p) sim[i][p] = 0.f;

            const int row = h + dy - 3;
            if (row >= 0 && row < Hdim) {
                const float* xr = xb + row * Wdim + cp * HW;
                const float* xc = xb + h   * Wdim + cp * HW;
                for (int i = 0; i < 64; ++i) {
                    float f[12];
                    if (w4 > 0) {
                        f4 v = *(const f4*)(xr + w0 - 4);
                        f[0]=v.x; f[1]=v.y; f[2]=v.z; f[3]=v.w;
                    } else {
                        f[0]=0.f; f[1]=0.f; f[2]=0.f; f[3]=0.f;
                    }
                    {
                        f4 v = *(const f4*)(xr + w0);
                        f[4]=v.x; f[5]=v.y; f[6]=v.z; f[7]=v.w;
                    }
                    if (w4 < 15) {
                        f4 v = *(const f4*)(xr + w0 + 4);
                        f[8]=v.x; f[9]=v.y; f[10]=v.z; f[11]=v.w;
                    } else {
                        f[8]=0.f; f[9]=0.f; f[10]=0.f; f[11]=0.f;
                    }
                    f4 cen = *(const f4*)(xc + w0);
                    #pragma unroll
                    for (int dx = 0; dx < 7; ++dx)
                        #pragma unroll
                        for (int p = 0; p < 4; ++p)
                            sim[dx][p] += cen[p] * f[dx + p + 1];
                    xr += 4 * HW;
                    xc += 4 * HW;
                }
            }
            // reduce over the 4 channel partitions (lane bits 4..5)
            #pragma unroll
            for (int dx = 0; dx < 7; ++dx)
                #pragma unroll
                for (int p = 0; p < 4; ++p) {
                    float v = sim[dx][p];
                    v += __shfl_xor(v, 16);
                    v += __shfl_xor(v, 32);
                    sim[dx][p] = v;
                }
            if (cp == 0) {
                #pragma unroll
                for (int dx = 0; dx < 7; ++dx)
                    *(f4*)&simRed[dy * 7 + dx][w0] = *(const f4*)sim[dx];
            }
        }
    }
    __syncthreads();

    // ---------------- Softmax over k=49 ----------------
    {
        const int w  = t & 63;
        const int kc = t >> 6;   // 0..7 ; kc==7 idle
        float sred[7], e[7];
        if (kc < 7) {
            float lmax = -3.0e38f;
            #pragma unroll
            for (int j = 0; j < 7; ++j) {
                float s = simRed[kc * 7 + j][w];
                sred[j] = s;
                lmax = fmaxf(lmax, s);
            }
            redBuf[kc][w] = lmax;
        }
        __syncthreads();
        if (kc < 7) {
            float m = redBuf[0][w];
            #pragma unroll
            for (int q = 1; q < 7; ++q) m = fmaxf(m, redBuf[q][w]);
            float ps = 0.f;
            #pragma unroll
            for (int j = 0; j < 7; ++j) {
                e[j] = __expf(sred[j] - m);
                ps += e[j];
            }
            psumBuf[kc][w] = ps;
        }
        __syncthreads();
        if (kc < 7) {
            float l = psumBuf[0][w];
            #pragma unroll
            for (int q = 1; q < 7; ++q) l += psumBuf[q][w];
            float rinv = 1.0f / l;
            #pragma unroll
            for (int j = 0; j < 7; ++j)
                attnBuf[kc * 7 + j][w] = e[j] * rinv;
        }
    }
    __syncthreads();

    // ---------------- Phase B: out[c][w] = sum_k attn[k]*x[c,nbr] ----------------
    {
        const int w4 = t & 15;
        const int ci = t >> 4;      // 0..31 -> 8 channels each
        const int w0 = w4 * 4;
        const int c0 = ci * 8;

        float acc[8][4];
        #pragma unroll
        for (int ch = 0; ch < 8; ++ch)
            #pragma unroll
            for (int p = 0; p < 4; ++p) acc[ch][p] = 0.f;

        for (int dy = 0; dy < 7; ++dy) {
            const int row = h + dy - 3;
            if (row < 0 || row >= Hdim) continue;   // block-uniform branch
            float a[7][4];
            #pragma unroll
            for (int dx = 0; dx < 7; ++dx) {
                f4 v = *(const f4*)&attnBuf[dy * 7 + dx][w0];
                a[dx][0]=v.x; a[dx][1]=v.y; a[dx][2]=v.z; a[dx][3]=v.w;
            }
            const float* xr = xb + c0 * HW + row * Wdim;
            #pragma unroll
            for (int ch = 0; ch < 8; ++ch) {
                float f[12];
                if (w4 > 0) {
                    f4 v = *(const f4*)(xr + w0 - 4);
                    f[0]=v.x; f[1]=v.y; f[2]=v.z; f[3]=v.w;
                } else {
                    f[0]=0.f; f[1]=0.f; f[2]=0.f; f[3]=0.f;
                }
                {
                    f4 v = *(const f4*)(xr + w0);
                    f[4]=v.x; f[5]=v.y; f[6]=v.z; f[7]=v.w;
                }
                if (w4 < 15) {
                    f4 v = *(const f4*)(xr + w0 + 4);
                    f[8]=v.x; f[9]=v.y; f[10]=v.z; f[11]=v.w;
                } else {
                    f[8]=0.f; f[9]=0.f; f[10]=0.f; f[11]=0.f;
                }
                #pragma unroll
                for (int dx = 0; dx < 7; ++dx)
                    #pragma unroll
                    for (int p = 0; p < 4; ++p)
                        acc[ch][p] += a[dx][p] * f[dx + p + 1];
                xr += HW;
            }
        }

        float* ob = out + (size_t)b * (Cdim * HW) + h * Wdim;
        #pragma unroll
        for (int ch = 0; ch < 8; ++ch)
            *(f4*)(ob + (c0 + ch) * HW + w0) = *(const f4*)acc[ch];
    }
}

extern "C" void kernel_launch(void* const* d_in, const int* in_sizes, int n_in,
                              void* d_out, int out_size, void* d_ws, size_t ws_size,
                              hipStream_t stream)
{
    const float* x = (const float*)d_in[0];
    float* out = (float*)d_out;
    dim3 grid(Hdim, 4);  // (h, b)
    selfattn_kernel<<<grid, 512, 0, stream>>>(x, out);
}